// Round 1
// 82.580 us; speedup vs baseline: 1.0034x; 1.0034x over previous
//
#include <hip/hip_runtime.h>

// StateSpaceLayer: out[b,t,r,c] = sum_{j<=t} A[r]^(t-j) * x[b,j,r,c]
// == linear recurrence out[t] = A[r]*out[t-1] + x[t] along seq.
// Shapes: x (4,512,64,64) f32, A (64,) f32, out (4,512,64,64) f32.
//
// V2: float4-vectorized chunked scan.
//   grid  = 256 blocks, one per (batch b, row r)     [1 block/CU]
//   block = 1024 threads = 64 chunks x 16 float4-cols [16 waves/CU]
//   Each thread scans CHUNK=8 timesteps of a 4-wide column slice with
//   global_load/store_dwordx4 (1 KB per wave-instruction vs 256 B in V1).
//   Chunk-end states exchanged via LDS; carry = Horner over prior chunks
//   with multiplier a^8.

#define B_    4
#define SEQ_  512
#define D_    64
#define CH_   8                  // timesteps per chunk
#define NCH_  (SEQ_ / CH_)       // 64 chunks
#define NCQ_  (D_ / 4)           // 16 float4 columns
#define NTHR_ (NCH_ * NCQ_)      // 1024 threads per block

__global__ __launch_bounds__(NTHR_) void ssm_scan_kernel(
    const float* __restrict__ x, const float* __restrict__ A,
    float* __restrict__ out)
{
    __shared__ float4 Elds[NCH_][NCQ_];   // 16 KB: chunk-end states

    const int blk = blockIdx.x;          // 0 .. B_*D_-1
    const int bi  = blk >> 6;            // batch index
    const int r   = blk & 63;            // row (decay) index
    const int tid = threadIdx.x;
    const int ch  = tid >> 4;            // chunk id 0..63
    const int cq  = tid & 15;            // float4 column 0..15

    const float a = fmaxf(A[r], 1e-6f);  // clip like reference (EPS=1e-6)

    const int j0 = ch * CH_;
    // flat float index of x[bi, j0, r, cq*4]
    const size_t base = ((size_t)(bi * SEQ_ + j0) * D_ + r) * D_ + cq * 4;
    const float4* xp = (const float4*)(x + base);
    float4*       op = (float4*)(out + base);
    const int jstride4 = (D_ * D_) / 4;  // 1024 float4 between timesteps

    // Phase 1: local scan of this chunk with zero initial state.
    float4 loc[CH_];
    float s0 = 0.f, s1 = 0.f, s2 = 0.f, s3 = 0.f;
    #pragma unroll
    for (int t = 0; t < CH_; ++t) {
        float4 v = xp[(size_t)t * jstride4];
        s0 = fmaf(s0, a, v.x);
        s1 = fmaf(s1, a, v.y);
        s2 = fmaf(s2, a, v.z);
        s3 = fmaf(s3, a, v.w);
        loc[t] = make_float4(s0, s1, s2, s3);
    }

    // Publish chunk-end state.
    Elds[ch][cq] = make_float4(s0, s1, s2, s3);
    __syncthreads();

    // a^CH_ (= a^8) via 3 squarings.
    float a2 = a * a, a4 = a2 * a2, aL = a4 * a4;

    // Carry into this chunk = scan state after chunk ch-1:
    //   S_{ch-1} = sum_{cp<ch} aL^(ch-1-cp) * E_cp   (Horner, low->high)
    float c0 = 0.f, c1 = 0.f, c2 = 0.f, c3 = 0.f;
    for (int cp = 0; cp < ch; ++cp) {
        float4 e = Elds[cp][cq];
        c0 = fmaf(c0, aL, e.x);
        c1 = fmaf(c1, aL, e.y);
        c2 = fmaf(c2, aL, e.z);
        c3 = fmaf(c3, aL, e.w);
    }

    // Phase 3: fix up with carry and store.  out[j0+t] = loc[t] + carry*a^(t+1)
    float p = a;
    #pragma unroll
    for (int t = 0; t < CH_; ++t) {
        float4 l = loc[t];
        float4 o;
        o.x = fmaf(c0, p, l.x);
        o.y = fmaf(c1, p, l.y);
        o.z = fmaf(c2, p, l.z);
        o.w = fmaf(c3, p, l.w);
        op[(size_t)t * jstride4] = o;
        p *= a;
    }
}

extern "C" void kernel_launch(void* const* d_in, const int* in_sizes, int n_in,
                              void* d_out, int out_size, void* d_ws, size_t ws_size,
                              hipStream_t stream) {
    const float* x   = (const float*)d_in[0];
    const float* A   = (const float*)d_in[1];
    float*       out = (float*)d_out;

    dim3 grid(B_ * D_);            // 256 blocks, one per (batch, r)
    dim3 block(NTHR_);             // 1024 threads = 16 waves
    hipLaunchKernelGGL(ssm_scan_kernel, grid, block, 0, stream, x, A, out);
}